// Round 8
// baseline (486.630 us; speedup 1.0000x reference)
//
#include <hip/hip_runtime.h>
#include <hip/hip_bf16.h>
#include <math.h>

#define TOK   4096
#define DIM   1024
#define DMLP  4096
#define NE    8
#define BM    128
#define BN    128
#define BN2   64
#define BK    128
#define PADMAX (TOK + NE * BM)   // 5120 padded slots
#define NTILES (PADMAX / BM)     // 40 row-tiles
#define MAXSUP 24                // max 256-row supertiles

typedef __attribute__((ext_vector_type(8))) short  short8;
typedef __attribute__((ext_vector_type(4))) float  float4v;
typedef __attribute__((ext_vector_type(4))) unsigned short ushort4v;
typedef __attribute__((ext_vector_type(2))) unsigned long long ull2;

// async global->LDS, 16 B per lane; LDS dest is wave-uniform base + lane*16
#define ASYNC16(gp, lp) __builtin_amdgcn_global_load_lds( \
    (const __attribute__((address_space(1))) unsigned int*)(gp), \
    (__attribute__((address_space(3))) unsigned int*)(lp), 16, 0, 0)

// BK=128: 16 granules (8 bf16 = 16 B each) per row. Involution on low 3 bits.
#define SWZ(R, C) (((C) & 8) | (((C) ^ (R)) & 7))
// LDS granule offset (in shorts) for row R, k-granule C
#define FRAG_OFF(R, C) ((((R) << 4) + SWZ(R, C)) << 3)

static __device__ __forceinline__ unsigned short f2bf(float f) {
  unsigned u = __float_as_uint(f);
  u += 0x7fffu + ((u >> 16) & 1u);
  return (unsigned short)(u >> 16);
}

// HW packed f32->bf16 RNE (identical rounding to f2bf), 2 elems / instr
static __device__ __forceinline__ unsigned cvt_pk_bf16(float lo, float hi) {
  unsigned r;
  asm("v_cvt_pk_bf16_f32 %0, %1, %2" : "=v"(r) : "v"(lo), "v"(hi));
  return r;
}

// exact-erf GELU via Abramowitz&Stegun 7.1.26 (|err| < 1.5e-7)
static __device__ __forceinline__ float gelu_erf(float v) {
  const float x = fabsf(v) * 0.70710678118654752f;
  const float t = __builtin_amdgcn_rcpf(1.0f + 0.3275911f * x);
  const float poly = ((((1.061405429f * t - 1.453152027f) * t + 1.421413741f) * t
                       - 0.284496736f) * t + 0.254829592f) * t;
  const float erf_abs = 1.0f - poly * __expf(-x * x);
  return 0.5f * v * (1.0f + copysignf(erf_abs, v));
}

// ---------------------------------------------------------------------------
// Kernel 1: group tokens by expert (single block). 128-tile map + 256-row
// supertile descriptors (two same-expert 128-tiles; odd leftover self-pairs).
// ---------------------------------------------------------------------------
__global__ void group_kernel(const int* __restrict__ eidx,
                             int* __restrict__ perm,
                             int* __restrict__ tile_e,
                             int* __restrict__ supA,
                             int* __restrict__ supB,
                             int* __restrict__ supE) {
  __shared__ int cnt[NE], off[NE], len[NE], cur[NE];
  const int tid = threadIdx.x;
  if (tid < NE) cnt[tid] = 0;
  __syncthreads();
  for (int i = tid; i < TOK; i += 256) atomicAdd(&cnt[eidx[i]], 1);
  __syncthreads();
  if (tid == 0) {
    int o = 0;
    for (int e = 0; e < NE; e++) {
      off[e] = o;
      len[e] = ((cnt[e] + BM - 1) / BM) * BM;
      cur[e] = o;
      o += len[e];
    }
    int ns = 0;
    for (int e = 0; e < NE; e++) {
      const int nt = len[e] / BM;
      for (int p = 0; p < nt; p += 2) {
        const int pb = (p + 1 < nt) ? (p + 1) : p;
        supA[ns] = off[e] + p * BM;
        supB[ns] = off[e] + pb * BM;
        supE[ns] = e;
        ns++;
      }
    }
    for (; ns < MAXSUP; ns++) { supA[ns] = 0; supB[ns] = 0; supE[ns] = -1; }
  }
  __syncthreads();
  for (int s = tid; s < PADMAX; s += 256) perm[s] = -1;
  __syncthreads();
  for (int i = tid; i < TOK; i += 256) {
    const int e = eidx[i];
    const int p = atomicAdd(&cur[e], 1);
    perm[p] = i;
  }
  __syncthreads();
  for (int t = tid; t < NTILES; t += 256) {
    const int row = t * BM;
    int te = -1;
    for (int e = 0; e < NE; e++)
      if (row >= off[e] && row < off[e] + len[e]) te = e;
    tile_e[t] = te;
  }
}

// ---------------------------------------------------------------------------
// Kernel 2: gather + convert x rows into permuted bf16 [PADMAX][DIM]
// ---------------------------------------------------------------------------
__global__ __launch_bounds__(256)
void xgather_kernel(const float* __restrict__ x, const int* __restrict__ perm,
                    unsigned short* __restrict__ xg) {
  const int slot = blockIdx.x;
  const int t    = perm[slot];
  const int tid  = threadIdx.x;
  ushort4v o = (ushort4v){0, 0, 0, 0};
  if (t >= 0) {
    const float4v v = *(const float4v*)(x + (size_t)t * DIM + tid * 4);
#pragma unroll
    for (int q = 0; q < 4; q++) o[q] = f2bf(v[q]);
  }
  *(ushort4v*)(xg + (size_t)slot * DIM + tid * 4) = o;
}

// ---------------------------------------------------------------------------
// Kernel 3: h = gelu(xg @ W1 + b1) -> bf16. 128x128 tile, BK=128.
// B staged DIRECTLY from f32 [K][N] W1: float4 loads (8x128B segs/instr),
// v_cvt_pk_bf16_f32, swizzled ds_write_b64 into the proven FRAG_OFF layout
// (<=4-way write conflicts). Deletes the standalone weight-transpose pass.
// Grid: (DMLP/BN, NTILES) col-fastest -> B panel sharers on one XCD.
// ---------------------------------------------------------------------------
__global__ __launch_bounds__(256)
void gemm1_kernel(const unsigned short* __restrict__ xg,
                  const float* __restrict__ W1,
                  const float* __restrict__ b1, const int* __restrict__ tile_e,
                  unsigned short* __restrict__ h) {
  const int bt = blockIdx.y;                 // row tile
  const int te = tile_e[bt];
  if (te < 0) return;
  const int n0 = blockIdx.x * BN;            // col tile
  const unsigned short* Asrc = xg + (size_t)bt * BM * DIM;
  const float* Bsrc = W1 + (size_t)te * DIM * DMLP + n0;   // [K][N], stride DMLP
  const int tid = threadIdx.x;

  // 64 KB: A = [0, BM*BK), B = [BM*BK, 2*BM*BK). A region reused in epilogue.
  __shared__ __align__(16) unsigned short SMEM[2 * BM * BK];

  // A staging map (ASYNC16, unchanged)
  const int rr = tid >> 4, q = tid & 15;
  const int cs = SWZ(rr, q);
  const unsigned short* a0 = Asrc + (size_t)rr * DIM + cs * 8;

  // B reg-staging map: thread-tile 4k x 4n; tk = tid&7, t3 = tid>>3
  const int tk = tid & 7, t3 = tid >> 3;     // t3: 0..31 (n-tile)

  const int wid = tid >> 6, lane = tid & 63;
  const int wm = (wid >> 1) * 64, wn = (wid & 1) * 64;
  const int l15 = lane & 15, quad = lane >> 4;

  float4v acc[4][4];
#pragma unroll
  for (int i = 0; i < 4; i++)
#pragma unroll
    for (int j = 0; j < 4; j++) acc[i][j] = (float4v){0.f, 0.f, 0.f, 0.f};

  for (int k0 = 0; k0 < DIM; k0 += BK) {
    // B: load 4 tiles of 4k x 4n f32, convert, swizzled LDS write
#pragma unroll
    for (int p = 0; p < 4; p++) {
      const int kt  = tk + p * 8;            // k-tile 0..31
      const int k0t = kt * 4;
      float4v v[4];
#pragma unroll
      for (int j = 0; j < 4; j++)
        v[j] = *(const float4v*)(Bsrc + (size_t)(k0 + k0t + j) * DMLP + t3 * 4);
      const int C = k0t >> 3, h2 = kt & 1;
#pragma unroll
      for (int qq = 0; qq < 4; qq++) {
        const int n = t3 * 4 + qq;
        const unsigned w0 = cvt_pk_bf16(v[0][qq], v[1][qq]);
        const unsigned w1 = cvt_pk_bf16(v[2][qq], v[3][qq]);
        *(unsigned long long*)&SMEM[BM * BK + FRAG_OFF(n, C) + h2 * 4] =
            ((unsigned long long)w1 << 32) | w0;
      }
    }
    // A: async global->LDS
#pragma unroll
    for (int t = 0; t < 8; t++)
      ASYNC16(a0 + (size_t)(16 * t) * DIM + k0, &SMEM[(t * 256 + tid) * 8]);
    __syncthreads();

#pragma unroll
    for (int hh = 0; hh < 4; hh++) {
      short8 a[4], b[4];
      const int C = hh * 4 + quad;
#pragma unroll
      for (int i = 0; i < 4; i++)
        a[i] = *(const short8*)&SMEM[FRAG_OFF(wm + i * 16 + l15, C)];
#pragma unroll
      for (int j = 0; j < 4; j++)
        b[j] = *(const short8*)&SMEM[BM * BK + FRAG_OFF(wn + j * 16 + l15, C)];
#pragma unroll
      for (int i = 0; i < 4; i++)
#pragma unroll
        for (int j = 0; j < 4; j++)
          acc[i][j] = __builtin_amdgcn_mfma_f32_16x16x32_bf16(a[i], b[j], acc[i][j], 0, 0, 0);
    }
    __syncthreads();
  }

  // ---- epilogue: gelu -> bf16 into LDS tile, then coalesced wide stores ----
#pragma unroll
  for (int i = 0; i < 4; i++) {
#pragma unroll
    for (int j = 0; j < 4; j++) {
      const int colL = wn + j * 16 + l15;
      const float bias = b1[te * DMLP + n0 + colL];
#pragma unroll
      for (int r = 0; r < 4; r++) {
        const int rowL = wm + i * 16 + quad * 4 + r;
        SMEM[rowL * BN + colL] = f2bf(gelu_erf(acc[i][j][r] + bias));
      }
    }
  }
  __syncthreads();
  const int gg = tid & 15;
  const int rb = tid >> 4;
#pragma unroll
  for (int p = 0; p < 8; p++) {
    const int rowL = rb + p * 16;
    const ull2 v = *(const ull2*)&SMEM[rowL * BN + gg * 8];
    *(ull2*)&h[(size_t)(bt * BM + rowL) * DMLP + n0 + gg * 8] = v;
  }
}

// ---------------------------------------------------------------------------
// Kernel 4: out[tok] = h @ W2 + b2, scatter. 256x64 supertile, BK=128.
// B staged directly from f32 [K][N] W2 (same reg-stage scheme, 2 tiles/thr).
// LDS 80 KB -> 2 blocks/CU. Grid: (DIM/64, MAXSUP) col-fastest.
// ---------------------------------------------------------------------------
__global__ __launch_bounds__(256)
void gemm2_kernel(const unsigned short* __restrict__ h,
                  const float* __restrict__ W2,
                  const float* __restrict__ b2, const int* __restrict__ perm,
                  const int* __restrict__ supA, const int* __restrict__ supB,
                  const int* __restrict__ supE, float* __restrict__ out) {
  const int s  = blockIdx.y;
  const int te = supE[s];
  if (te < 0) return;
  const int rowA = supA[s], rowB = supB[s];
  const int n0 = blockIdx.x * BN2;
  const int tid = threadIdx.x;

  __shared__ __align__(16) unsigned short As[256 * BK];   // 64 KB
  __shared__ __align__(16) unsigned short Bs[BN2 * BK];   // 16 KB

  const int rr = tid >> 4, q = tid & 15;
  const int cs = SWZ(rr, q);
  const unsigned short* aA = h + (size_t)(rowA + rr) * DMLP + cs * 8;
  const unsigned short* aB = h + (size_t)(rowB + rr) * DMLP + cs * 8;
  const float* Bsrc = W2 + (size_t)te * DMLP * DIM + n0;   // [K][N], stride DIM

  const int tk = tid & 7, t3 = tid >> 3;
  const int nt = t3 & 15;                    // n-tile 0..15
  const int kh = t3 >> 4;                    // 0/1: extra k-tile offset

  const int wid = tid >> 6, lane = tid & 63;
  const int wm = wid * 64;                   // 64 rows per wave
  const int l15 = lane & 15, quad = lane >> 4;

  float4v acc[4][4];
#pragma unroll
  for (int i = 0; i < 4; i++)
#pragma unroll
    for (int j = 0; j < 4; j++) acc[i][j] = (float4v){0.f, 0.f, 0.f, 0.f};

  for (int k0 = 0; k0 < DMLP; k0 += BK) {
    // B: 2 tiles of 4k x 4n f32 per thread
#pragma unroll
    for (int p = 0; p < 2; p++) {
      const int kt  = tk + kh * 8 + p * 16;  // 0..31
      const int k0t = kt * 4;
      float4v v[4];
#pragma unroll
      for (int j = 0; j < 4; j++)
        v[j] = *(const float4v*)(Bsrc + (size_t)(k0 + k0t + j) * DIM + nt * 4);
      const int C = k0t >> 3, h2 = kt & 1;
#pragma unroll
      for (int qq = 0; qq < 4; qq++) {
        const int n = nt * 4 + qq;
        const unsigned w0 = cvt_pk_bf16(v[0][qq], v[1][qq]);
        const unsigned w1 = cvt_pk_bf16(v[2][qq], v[3][qq]);
        *(unsigned long long*)&Bs[FRAG_OFF(n, C) + h2 * 4] =
            ((unsigned long long)w1 << 32) | w0;
      }
    }
    // A: async global->LDS, two 128-row halves
#pragma unroll
    for (int t = 0; t < 8; t++)
      ASYNC16(aA + (size_t)(16 * t) * DMLP + k0, &As[(t * 256 + tid) * 8]);
#pragma unroll
    for (int t = 0; t < 8; t++)
      ASYNC16(aB + (size_t)(16 * t) * DMLP + k0, &As[((t + 8) * 256 + tid) * 8]);
    __syncthreads();

#pragma unroll
    for (int hh = 0; hh < 4; hh++) {
      short8 a[4], b[4];
      const int C = hh * 4 + quad;
#pragma unroll
      for (int i = 0; i < 4; i++)
        a[i] = *(const short8*)&As[FRAG_OFF(wm + i * 16 + l15, C)];
#pragma unroll
      for (int j = 0; j < 4; j++)
        b[j] = *(const short8*)&Bs[FRAG_OFF(j * 16 + l15, C)];
#pragma unroll
      for (int i = 0; i < 4; i++)
#pragma unroll
        for (int j = 0; j < 4; j++)
          acc[i][j] = __builtin_amdgcn_mfma_f32_16x16x32_bf16(a[i], b[j], acc[i][j], 0, 0, 0);
    }
    __syncthreads();
  }

  const int halfbase = (wm < 128) ? (rowA + wm) : (rowB + (wm - 128));
#pragma unroll
  for (int i = 0; i < 4; i++) {
#pragma unroll
    for (int j = 0; j < 4; j++) {
      const int col = n0 + j * 16 + l15;
      const float bias = b2[te * DIM + col];
#pragma unroll
      for (int r = 0; r < 4; r++) {
        const int slot = halfbase + i * 16 + quad * 4 + r;
        const int t    = perm[slot];
        if (t >= 0) out[(size_t)t * DIM + col] = acc[i][j][r] + bias;
      }
    }
  }
}

// ---------------------------------------------------------------------------
extern "C" void kernel_launch(void* const* d_in, const int* in_sizes, int n_in,
                              void* d_out, int out_size, void* d_ws, size_t ws_size,
                              hipStream_t stream) {
  const float* x    = (const float*)d_in[0];
  const int*   eidx = (const int*)d_in[1];
  const float* W1   = (const float*)d_in[2];
  const float* b1   = (const float*)d_in[3];
  const float* W2   = (const float*)d_in[4];
  const float* b2   = (const float*)d_in[5];
  float* out = (float*)d_out;

  char* ws = (char*)d_ws;
  int* perm   = (int*)ws;                              // 5120 ints
  int* tile_e = (int*)(ws + PADMAX * sizeof(int));     // 40 ints
  int* supA   = (int*)(ws + 20736);                    // 24 ints
  int* supB   = (int*)(ws + 20832);                    // 24 ints
  int* supE   = (int*)(ws + 20928);                    // 24 ints
  unsigned short* xg  = (unsigned short*)(ws + 32768);                      // 10 MB
  unsigned short* h   = (unsigned short*)(ws + 32768 + 10485760);           // 40 MB

  group_kernel<<<1, 256, 0, stream>>>(eidx, perm, tile_e, supA, supB, supE);
  xgather_kernel<<<PADMAX, 256, 0, stream>>>(x, perm, xg);
  gemm1_kernel<<<dim3(DMLP / BN, NTILES), 256, 0, stream>>>(xg, W1, b1, tile_e, h);
  gemm2_kernel<<<dim3(DIM / BN2, MAXSUP), 256, 0, stream>>>(h, W2, b2, perm, supA, supB, supE, out);
}

// Round 9
// 463.931 us; speedup vs baseline: 1.0489x; 1.0489x over previous
//
#include <hip/hip_runtime.h>
#include <hip/hip_bf16.h>
#include <math.h>

#define TOK   4096
#define DIM   1024
#define DMLP  4096
#define NE    8
#define BM    128
#define BN    128
#define BN2   64
#define BK    128
#define PADMAX (TOK + NE * BM)   // 5120 padded slots
#define NTILES (PADMAX / BM)     // 40 row-tiles
#define MAXSUP 24                // max 256-row supertiles

typedef __attribute__((ext_vector_type(8))) short  short8;
typedef __attribute__((ext_vector_type(4))) float  float4v;
typedef __attribute__((ext_vector_type(4))) unsigned short ushort4v;
typedef __attribute__((ext_vector_type(2))) unsigned long long ull2;

// async global->LDS, 16 B per lane; LDS dest is wave-uniform base + lane*16
#define ASYNC16(gp, lp) __builtin_amdgcn_global_load_lds( \
    (const __attribute__((address_space(1))) unsigned int*)(gp), \
    (__attribute__((address_space(3))) unsigned int*)(lp), 16, 0, 0)

// A-side LDS layout (row-major, swizzled): BK=128 -> 16 granules/row
#define SWZ(R, C) (((C) & 8) | (((C) ^ (R)) & 7))
#define FRAG_OFF(R, C) ((((R) << 4) + SWZ(R, C)) << 3)
// B-side LDS layout (granule-major): [C][n][8], offset in shorts
#define BOFF(C, n) ((((C) << 7) + (n)) << 3)

static __device__ __forceinline__ unsigned short f2bf(float f) {
  unsigned u = __float_as_uint(f);
  u += 0x7fffu + ((u >> 16) & 1u);
  return (unsigned short)(u >> 16);
}

// exact-erf GELU via Abramowitz&Stegun 7.1.26 (|err| < 1.5e-7)
static __device__ __forceinline__ float gelu_erf(float v) {
  const float x = fabsf(v) * 0.70710678118654752f;
  const float t = __builtin_amdgcn_rcpf(1.0f + 0.3275911f * x);
  const float poly = ((((1.061405429f * t - 1.453152027f) * t + 1.421413741f) * t
                       - 0.284496736f) * t + 0.254829592f) * t;
  const float erf_abs = 1.0f - poly * __expf(-x * x);
  return 0.5f * v * (1.0f + copysignf(erf_abs, v));
}

// ---------------------------------------------------------------------------
// Kernel 1: group tokens by expert (single block). 128-tile map + 256-row
// supertile descriptors (two same-expert 128-tiles; odd leftover self-pairs).
// ---------------------------------------------------------------------------
__global__ void group_kernel(const int* __restrict__ eidx,
                             int* __restrict__ perm,
                             int* __restrict__ tile_e,
                             int* __restrict__ supA,
                             int* __restrict__ supB,
                             int* __restrict__ supE) {
  __shared__ int cnt[NE], off[NE], len[NE], cur[NE];
  const int tid = threadIdx.x;
  if (tid < NE) cnt[tid] = 0;
  __syncthreads();
  for (int i = tid; i < TOK; i += 256) atomicAdd(&cnt[eidx[i]], 1);
  __syncthreads();
  if (tid == 0) {
    int o = 0;
    for (int e = 0; e < NE; e++) {
      off[e] = o;
      len[e] = ((cnt[e] + BM - 1) / BM) * BM;
      cur[e] = o;
      o += len[e];
    }
    int ns = 0;
    for (int e = 0; e < NE; e++) {
      const int nt = len[e] / BM;
      for (int p = 0; p < nt; p += 2) {
        const int pb = (p + 1 < nt) ? (p + 1) : p;
        supA[ns] = off[e] + p * BM;
        supB[ns] = off[e] + pb * BM;
        supE[ns] = e;
        ns++;
      }
    }
    for (; ns < MAXSUP; ns++) { supA[ns] = 0; supB[ns] = 0; supE[ns] = -1; }
  }
  __syncthreads();
  for (int s = tid; s < PADMAX; s += 256) perm[s] = -1;
  __syncthreads();
  for (int i = tid; i < TOK; i += 256) {
    const int e = eidx[i];
    const int p = atomicAdd(&cur[e], 1);
    perm[p] = i;
  }
  __syncthreads();
  for (int t = tid; t < NTILES; t += 256) {
    const int row = t * BM;
    int te = -1;
    for (int e = 0; e < NE; e++)
      if (row >= off[e] && row < off[e] + len[e]) te = e;
    tile_e[t] = te;
  }
}

// ---------------------------------------------------------------------------
// convpack body: W [K][N] f32 -> WT [K/8][N][8] bf16 (k-granule layout).
// NO LDS, NO transpose: float4 coalesced reads (4 KB/row/block), fully
// contiguous 16 B/thread writes (16 KB/block). Both sides dense.
// Block handles k-granule kg, n-range [n0, n0+1024).
// ---------------------------------------------------------------------------
static __device__ __forceinline__
void convpack_body(const float* __restrict__ W, unsigned short* __restrict__ WT,
                   int K, int N, int kg, int nblk, int e, int tid) {
  const int n0 = nblk * 1024 + tid * 4;
  const float* Win = W + (size_t)e * K * N + (size_t)kg * 8 * N + n0;
  unsigned short* Wout = WT + (size_t)e * K * N + ((size_t)kg * N + n0) * 8;
  float4v v[8];
#pragma unroll
  for (int j = 0; j < 8; j++) v[j] = *(const float4v*)(Win + (size_t)j * N);
#pragma unroll
  for (int q = 0; q < 4; q++) {
    short8 g;
#pragma unroll
    for (int j = 0; j < 8; j++) g[j] = (short)f2bf(v[j][q]);
    *(short8*)(Wout + q * 8) = g;
  }
}

// ---------------------------------------------------------------------------
// Kernel 2 (merged prep): convpack(W1) + convpack(W2) + xgather, ONE launch.
// W1: K=1024,N=4096 -> 128 kg x 4 nblk x 8 e = 4096 blocks
// W2: K=4096,N=1024 -> 512 kg x 1 nblk x 8 e = 4096 blocks
// xgather: 5120 blocks. Total 13312.
// ---------------------------------------------------------------------------
__global__ __launch_bounds__(256)
void prep_kernel(const float* __restrict__ W1, unsigned short* __restrict__ W1T,
                 const float* __restrict__ W2, unsigned short* __restrict__ W2T,
                 const float* __restrict__ x, const int* __restrict__ perm,
                 unsigned short* __restrict__ xg) {
  const int bid = blockIdx.x;
  const int tid = threadIdx.x;
  if (bid < 4096) {
    // W1: kg = bid & 127, nblk = (bid>>7)&3, e = bid>>9
    convpack_body(W1, W1T, DIM, DMLP, bid & 127, (bid >> 7) & 3, bid >> 9, tid);
  } else if (bid < 8192) {
    const int b = bid - 4096;
    // W2: kg = b & 511, e = b>>9
    convpack_body(W2, W2T, DMLP, DIM, b & 511, 0, b >> 9, tid);
  } else {
    const int slot = bid - 8192;
    const int t    = perm[slot];
    ushort4v o = (ushort4v){0, 0, 0, 0};
    if (t >= 0) {
      const float4v v = *(const float4v*)(x + (size_t)t * DIM + tid * 4);
#pragma unroll
      for (int q = 0; q < 4; q++) o[q] = f2bf(v[q]);
    }
    *(ushort4v*)(xg + (size_t)slot * DIM + tid * 4) = o;
  }
}

// ---------------------------------------------------------------------------
// Kernel 3: h = gelu(xg @ W1 + b1) -> bf16. 128x128 tile, BK=128.
// A: row-major swizzled (unchanged). B: granule-major [C][128][8] staged by
// ASYNC16 from WT's [K/8][N][8] layout -> 1 KB contiguous source segments;
// MFMA b-read = 256 B contiguous per 16-lane group (2-way, free).
// Grid: (DMLP/BN, NTILES) col-fastest for XCD L2 reuse of B panels.
// ---------------------------------------------------------------------------
__global__ __launch_bounds__(256)
void gemm1_kernel(const unsigned short* __restrict__ xg,
                  const unsigned short* __restrict__ W1T,
                  const float* __restrict__ b1, const int* __restrict__ tile_e,
                  unsigned short* __restrict__ h) {
  const int bt = blockIdx.y;                 // row tile
  const int te = tile_e[bt];
  if (te < 0) return;
  const int n0 = blockIdx.x * BN;            // col tile
  const unsigned short* Asrc = xg + (size_t)bt * BM * DIM;
  // granule base for (kg=0, n=n0)
  const unsigned short* Bsrc = W1T + (size_t)te * DIM * DMLP + (size_t)n0 * 8;
  const int tid = threadIdx.x;

  // 64 KB: A = [0, BM*BK) row-major swz; B = [BM*BK, 2*BM*BK) granule-major.
  __shared__ __align__(16) unsigned short SMEM[2 * BM * BK];

  // A staging (unchanged)
  const int rr = tid >> 4, q = tid & 15;
  const int cs = SWZ(rr, q);
  const unsigned short* a0 = Asrc + (size_t)rr * DIM + cs * 8;
  // B staging: granule p = t*256 + tid -> C = p>>7, n = p&127
  const int bC = tid >> 7, bn = tid & 127;   // t adds 2 to C per step
  const unsigned short* b0 = Bsrc + ((size_t)bC * DMLP + bn) * 8;

  const int wid = tid >> 6, lane = tid & 63;
  const int wm = (wid >> 1) * 64, wn = (wid & 1) * 64;
  const int l15 = lane & 15, quad = lane >> 4;

  float4v acc[4][4];
#pragma unroll
  for (int i = 0; i < 4; i++)
#pragma unroll
    for (int j = 0; j < 4; j++) acc[i][j] = (float4v){0.f, 0.f, 0.f, 0.f};

  for (int k0 = 0; k0 < DIM; k0 += BK) {
    const int kg0 = k0 >> 3;                 // granule row of this K-step
#pragma unroll
    for (int t = 0; t < 8; t++)
      ASYNC16(a0 + (size_t)(16 * t) * DIM + k0, &SMEM[(t * 256 + tid) * 8]);
#pragma unroll
    for (int t = 0; t < 8; t++)
      ASYNC16(b0 + (size_t)(kg0 + 2 * t) * DMLP * 8,
              &SMEM[BM * BK + (t * 256 + tid) * 8]);
    __syncthreads();

#pragma unroll
    for (int hh = 0; hh < 4; hh++) {
      short8 a[4], b[4];
      const int C = hh * 4 + quad;
#pragma unroll
      for (int i = 0; i < 4; i++)
        a[i] = *(const short8*)&SMEM[FRAG_OFF(wm + i * 16 + l15, C)];
#pragma unroll
      for (int j = 0; j < 4; j++)
        b[j] = *(const short8*)&SMEM[BM * BK + BOFF(C, wn + j * 16 + l15)];
#pragma unroll
      for (int i = 0; i < 4; i++)
#pragma unroll
        for (int j = 0; j < 4; j++)
          acc[i][j] = __builtin_amdgcn_mfma_f32_16x16x32_bf16(a[i], b[j], acc[i][j], 0, 0, 0);
    }
    __syncthreads();
  }

  // ---- epilogue: gelu -> bf16 into LDS tile, then coalesced wide stores ----
#pragma unroll
  for (int i = 0; i < 4; i++) {
#pragma unroll
    for (int j = 0; j < 4; j++) {
      const int colL = wn + j * 16 + l15;
      const float bias = b1[te * DMLP + n0 + colL];
#pragma unroll
      for (int r = 0; r < 4; r++) {
        const int rowL = wm + i * 16 + quad * 4 + r;
        SMEM[rowL * BN + colL] = f2bf(gelu_erf(acc[i][j][r] + bias));
      }
    }
  }
  __syncthreads();
  const int gg = tid & 15;
  const int rb = tid >> 4;
#pragma unroll
  for (int p = 0; p < 8; p++) {
    const int rowL = rb + p * 16;
    const ull2 v = *(const ull2*)&SMEM[rowL * BN + gg * 8];
    *(ull2*)&h[(size_t)(bt * BM + rowL) * DMLP + n0 + gg * 8] = v;
  }
}

// ---------------------------------------------------------------------------
// Kernel 4: out[tok] = h @ W2 + b2, scatter. 256x64 supertile, BK=128.
// A rows 0-127 from supA, 128-255 from supB (same expert). B granule-major
// [16][64][8] staged from WT2 granule layout. LDS 80 KB -> 2 blocks/CU.
// Grid: (DIM/64, MAXSUP) col-fastest.
// ---------------------------------------------------------------------------
__global__ __launch_bounds__(256)
void gemm2_kernel(const unsigned short* __restrict__ h,
                  const unsigned short* __restrict__ W2T,
                  const float* __restrict__ b2, const int* __restrict__ perm,
                  const int* __restrict__ supA, const int* __restrict__ supB,
                  const int* __restrict__ supE, float* __restrict__ out) {
  const int s  = blockIdx.y;
  const int te = supE[s];
  if (te < 0) return;
  const int rowA = supA[s], rowB = supB[s];
  const int n0 = blockIdx.x * BN2;
  const int tid = threadIdx.x;

  __shared__ __align__(16) unsigned short As[256 * BK];   // 64 KB
  __shared__ __align__(16) unsigned short Bs[16 * BN2 * 8]; // 16 KB [C][64][8]

  const int rr = tid >> 4, q = tid & 15;
  const int cs = SWZ(rr, q);
  const unsigned short* aA = h + (size_t)(rowA + rr) * DMLP + cs * 8;
  const unsigned short* aB = h + (size_t)(rowB + rr) * DMLP + cs * 8;
  // B: granule p = t*256 + tid -> C = p>>6, n = p&63 (64 n per C-row)
  const int bC = tid >> 6, bn = tid & 63;    // t adds 4 to C per step
  const unsigned short* b0 = W2T + (size_t)te * DMLP * DIM
                           + ((size_t)bC * DIM + n0 + bn) * 8;

  const int wid = tid >> 6, lane = tid & 63;
  const int wm = wid * 64;                   // 64 rows per wave
  const int l15 = lane & 15, quad = lane >> 4;

  float4v acc[4][4];
#pragma unroll
  for (int i = 0; i < 4; i++)
#pragma unroll
    for (int j = 0; j < 4; j++) acc[i][j] = (float4v){0.f, 0.f, 0.f, 0.f};

  for (int k0 = 0; k0 < DMLP; k0 += BK) {
    const int kg0 = k0 >> 3;
#pragma unroll
    for (int t = 0; t < 8; t++)
      ASYNC16(aA + (size_t)(16 * t) * DMLP + k0, &As[(t * 256 + tid) * 8]);
#pragma unroll
    for (int t = 0; t < 8; t++)
      ASYNC16(aB + (size_t)(16 * t) * DMLP + k0, &As[((t + 8) * 256 + tid) * 8]);
#pragma unroll
    for (int t = 0; t < 4; t++)
      ASYNC16(b0 + (size_t)(kg0 + 4 * t) * DIM * 8, &Bs[(t * 256 + tid) * 8]);
    __syncthreads();

#pragma unroll
    for (int hh = 0; hh < 4; hh++) {
      short8 a[4], b[4];
      const int C = hh * 4 + quad;
#pragma unroll
      for (int i = 0; i < 4; i++)
        a[i] = *(const short8*)&As[FRAG_OFF(wm + i * 16 + l15, C)];
#pragma unroll
      for (int j = 0; j < 4; j++)
        b[j] = *(const short8*)&Bs[(((C) << 6) + j * 16 + l15) << 3];
#pragma unroll
      for (int i = 0; i < 4; i++)
#pragma unroll
        for (int j = 0; j < 4; j++)
          acc[i][j] = __builtin_amdgcn_mfma_f32_16x16x32_bf16(a[i], b[j], acc[i][j], 0, 0, 0);
    }
    __syncthreads();
  }

  const int halfbase = (wm < 128) ? (rowA + wm) : (rowB + (wm - 128));
#pragma unroll
  for (int i = 0; i < 4; i++) {
#pragma unroll
    for (int j = 0; j < 4; j++) {
      const int col = n0 + j * 16 + l15;
      const float bias = b2[te * DIM + col];
#pragma unroll
      for (int r = 0; r < 4; r++) {
        const int slot = halfbase + i * 16 + quad * 4 + r;
        const int t    = perm[slot];
        if (t >= 0) out[(size_t)t * DIM + col] = acc[i][j][r] + bias;
      }
    }
  }
}

// ---------------------------------------------------------------------------
extern "C" void kernel_launch(void* const* d_in, const int* in_sizes, int n_in,
                              void* d_out, int out_size, void* d_ws, size_t ws_size,
                              hipStream_t stream) {
  const float* x    = (const float*)d_in[0];
  const int*   eidx = (const int*)d_in[1];
  const float* W1   = (const float*)d_in[2];
  const float* b1   = (const float*)d_in[3];
  const float* W2   = (const float*)d_in[4];
  const float* b2   = (const float*)d_in[5];
  float* out = (float*)d_out;

  char* ws = (char*)d_ws;
  int* perm   = (int*)ws;                              // 5120 ints
  int* tile_e = (int*)(ws + PADMAX * sizeof(int));     // 40 ints
  int* supA   = (int*)(ws + 20736);                    // 24 ints
  int* supB   = (int*)(ws + 20832);                    // 24 ints
  int* supE   = (int*)(ws + 20928);                    // 24 ints
  unsigned short* xg  = (unsigned short*)(ws + 32768);                      // 10 MB
  unsigned short* h   = (unsigned short*)(ws + 32768 + 10485760);           // 40 MB
  unsigned short* W1T = (unsigned short*)(ws + 32768 + 10485760 + 41943040);// 64 MB
  unsigned short* W2T = (unsigned short*)((char*)W1T + 67108864);           // 64 MB

  group_kernel<<<1, 256, 0, stream>>>(eidx, perm, tile_e, supA, supB, supE);
  prep_kernel<<<8192 + PADMAX, 256, 0, stream>>>(W1, W1T, W2, W2T, x, perm, xg);
  gemm1_kernel<<<dim3(DMLP / BN, NTILES), 256, 0, stream>>>(xg, W1T, b1, tile_e, h);
  gemm2_kernel<<<dim3(DIM / BN2, MAXSUP), 256, 0, stream>>>(h, W2T, b2, perm, supA, supB, supE, out);
}